// Round 3
// baseline (413.862 us; speedup 1.0000x reference)
//
#include <hip/hip_runtime.h>
#include <hip/hip_bf16.h>
#include <math.h>

#define T_LEN 4096
#define BATCH 16

// ---------------------------------------------------------------------------
// Kernel 1: adapter + per-node GCN projection + A_HAT propagation + relu +
// node-mean pool.  Register-tiled GEMM form: thread = 4d x 4t, x staged
// transposed in LDS [c][t] so fragment reads are lane-varying ds_read_b128
// (no broadcast waste); all 18 gcn_w rows preloaded to registers -> the
// main loop has ZERO memory loads except LDS.
// Output h_pool stored channel-major [B][64][T].
// ---------------------------------------------------------------------------
__global__ __launch_bounds__(256) void k_gcn_pool(
    const float* __restrict__ x,      // [B][T][218]
    const float* __restrict__ gcn_w,  // [18][64]
    float* __restrict__ hp)           // [B][64][T]
{
    __shared__ float xt[218 * 68];    // [c][t], stride 68 (16B-aligned rows)

    const int b   = blockIdx.y;
    const int t0  = blockIdx.x * 64;
    const int tid = threadIdx.x;

    // coalesced load + transpose into LDS
    const float* xb = x + ((long)b * T_LEN + t0) * 218;
    #pragma unroll 1
    for (int i = tid; i < 64 * 218; i += 256) {
        const int t = i / 218;
        const int c = i - 218 * t;
        xt[c * 68 + t] = xb[i];
    }
    __syncthreads();

    const int dg = tid >> 4;          // 0..15: d-group of 4
    const int tt = tid & 15;          // 0..15: t-group of 4
    const int d0 = dg * 4;
    const int tb = tt * 4;

    // preload all weights for this thread's 4 output channels
    float wr[18][4];
    #pragma unroll
    for (int c = 0; c < 18; ++c)
        *(float4*)wr[c] = *(const float4*)(gcn_w + c * 64 + d0);

    const float cP = 1.0f / 6.0f;
    const float cS = 0.23570226039551584f;   // 1/sqrt(18)
    const float c3 = 1.0f / 3.0f;
    const float cT = 0.4082482904638631f;    // 1/sqrt(6)
    const float cH = 0.5f;

    // palm projection h0 (18 channels)
    float h0[4][4];
    #pragma unroll
    for (int di = 0; di < 4; ++di)
        #pragma unroll
        for (int ti = 0; ti < 4; ++ti) h0[di][ti] = 0.f;
    #pragma unroll
    for (int c = 0; c < 18; ++c) {
        float xv[4];
        *(float4*)xv = *(const float4*)(&xt[c * 68 + tb]);
        #pragma unroll
        for (int di = 0; di < 4; ++di)
            #pragma unroll
            for (int ti = 0; ti < 4; ++ti)
                h0[di][ti] = fmaf(wr[c][di], xv[ti], h0[di][ti]);
    }

    float pool[4][4], star[4][4];
    #pragma unroll
    for (int di = 0; di < 4; ++di)
        #pragma unroll
        for (int ti = 0; ti < 4; ++ti) { pool[di][ti] = 0.f; star[di][ti] = 0.f; }

    #pragma unroll 1
    for (int f = 0; f < 5; ++f) {
        float hn[4][4][4];            // [node][di][ti]
        #pragma unroll
        for (int n = 0; n < 4; ++n)
            #pragma unroll
            for (int di = 0; di < 4; ++di)
                #pragma unroll
                for (int ti = 0; ti < 4; ++ti) hn[n][di][ti] = 0.f;

        #pragma unroll
        for (int n = 0; n < 4; ++n) {
            const int cb = 18 + 10 * (4 * f + n);
            #pragma unroll
            for (int c = 0; c < 10; ++c) {
                float xv[4];
                *(float4*)xv = *(const float4*)(&xt[(cb + c) * 68 + tb]);
                #pragma unroll
                for (int di = 0; di < 4; ++di)
                    #pragma unroll
                    for (int ti = 0; ti < 4; ++ti)
                        hn[n][di][ti] = fmaf(wr[c][di], xv[ti], hn[n][di][ti]);
            }
        }

        #pragma unroll
        for (int di = 0; di < 4; ++di)
            #pragma unroll
            for (int ti = 0; ti < 4; ++ti) {
                const float ha = hn[0][di][ti], h2 = hn[1][di][ti];
                const float h3 = hn[2][di][ti], he = hn[3][di][ti];
                star[di][ti] += ha;
                const float pa = fmaf(cS, h0[di][ti], c3 * (ha + h2));
                const float pb = c3 * (ha + h2 + h3);
                const float pc = fmaf(cT, he, c3 * (h2 + h3));
                const float pe = fmaf(cT, h3, cH * he);
                pool[di][ti] += fmaxf(pa, 0.f) + fmaxf(pb, 0.f) +
                                fmaxf(pc, 0.f) + fmaxf(pe, 0.f);
            }
    }

    float* hpb = hp + (long)b * 64 * T_LEN + t0 + tb;
    #pragma unroll
    for (int di = 0; di < 4; ++di) {
        float r[4];
        #pragma unroll
        for (int ti = 0; ti < 4; ++ti) {
            const float p0 = fmaf(cP, h0[di][ti], cS * star[di][ti]);
            r[ti] = (pool[di][ti] + fmaxf(p0, 0.f)) * (1.0f / 21.0f);
        }
        *(float4*)(hpb + (long)(d0 + di) * T_LEN) = make_float4(r[0], r[1], r[2], r[3]);
    }
}

// ---------------------------------------------------------------------------
// MSTCN block, register-blocked + software-pipelined weight stream:
//   block = 256 threads = 16 j-groups x 16 t-threads; t-tile = 64.
//   Weight regs rotate in place: w[k] for column c+1 is loaded immediately
//   after the FMAs that consume w[k] for column c (~150-290 cyc of cover).
//   conv_out / head use 4-deep rotation (prefetch distance 4).
// ---------------------------------------------------------------------------
template <bool FINAL>
__global__ __launch_bounds__(256) void k_mstcn(
    const float* __restrict__ in,   // [B][64][T]
    const float* __restrict__ ws, const float* __restrict__ bs,
    const float* __restrict__ wm, const float* __restrict__ bm,
    const float* __restrict__ wl, const float* __restrict__ bl,
    const float* __restrict__ wo, const float* __restrict__ bo,
    float* __restrict__ out,        // [B][64][T]   (FINAL=false)
    const float* __restrict__ wd,   // [64][32]     (FINAL=true)
    const float* __restrict__ bd,   // [32]
    float* __restrict__ outp)       // [B][32]      (FINAL=true)
{
    __shared__ float smem[64 * 100];   // tile [c][96] stride 100; aliased later

    const int b   = blockIdx.y;
    const int t0  = blockIdx.x * 64;
    const int tid = threadIdx.x;
    const int jg  = tid >> 4;          // 0..15
    const int tt  = tid & 15;          // 0..15
    const int j0g = jg * 4;

    // ---- stage input window [t0-32, t0+63] as [c][96], row stride 100 ----
    const float* inb = in + (long)b * 64 * T_LEN;
    #pragma unroll 1
    for (int i = tid; i < 64 * 24; i += 256) {
        const int c = i / 24;
        const int q = i - c * 24;
        const int t = t0 - 32 + q * 4;
        float4 v = make_float4(0.f, 0.f, 0.f, 0.f);
        if (t >= 0) v = *(const float4*)(inb + (long)c * T_LEN + t);
        *(float4*)(&smem[c * 100 + q * 4]) = v;
    }
    __syncthreads();

    float acc[4][4];

    if (jg < 4) {
        // conv_s: k=3, d=1
        #pragma unroll
        for (int ji = 0; ji < 4; ++ji) {
            const float bv = bs[j0g + ji];
            #pragma unroll
            for (int ti = 0; ti < 4; ++ti) acc[ji][ti] = bv;
        }
        const float* wp = ws + j0g;              // + c*16 + k*1024
        float w[3][4];
        #pragma unroll
        for (int k = 0; k < 3; ++k) *(float4*)w[k] = *(const float4*)(wp + k * 1024);
        #pragma unroll 1
        for (int c = 0; c < 64; ++c) {
            const float4* rowq = (const float4*)(&smem[c * 100]);
            float win[8];
            *(float4*)(&win[0]) = rowq[tt + 7];
            *(float4*)(&win[4]) = rowq[tt + 8];
            const float* wn = wp + (c < 63 ? (c + 1) * 16 : 63 * 16);
            #pragma unroll
            for (int k = 0; k < 3; ++k) {
                const int off = 2 - k;
                #pragma unroll
                for (int ti = 0; ti < 4; ++ti) {
                    const float v = win[4 + ti - off];
                    #pragma unroll
                    for (int ji = 0; ji < 4; ++ji)
                        acc[ji][ti] = fmaf(w[k][ji], v, acc[ji][ti]);
                }
                *(float4*)w[k] = *(const float4*)(wn + k * 1024);
            }
        }
    } else if (jg < 8) {
        // conv_m: k=5, d=2
        #pragma unroll
        for (int ji = 0; ji < 4; ++ji) {
            const float bv = bm[j0g - 16 + ji];
            #pragma unroll
            for (int ti = 0; ti < 4; ++ti) acc[ji][ti] = bv;
        }
        const float* wp = wm + (j0g - 16);       // + c*16 + k*1024
        float w[5][4];
        #pragma unroll
        for (int k = 0; k < 5; ++k) *(float4*)w[k] = *(const float4*)(wp + k * 1024);
        #pragma unroll 1
        for (int c = 0; c < 64; ++c) {
            const float4* rowq = (const float4*)(&smem[c * 100]);
            float win[12];
            *(float4*)(&win[0]) = rowq[tt + 6];
            *(float4*)(&win[4]) = rowq[tt + 7];
            *(float4*)(&win[8]) = rowq[tt + 8];
            const float* wn = wp + (c < 63 ? (c + 1) * 16 : 63 * 16);
            #pragma unroll
            for (int k = 0; k < 5; ++k) {
                const int off = (4 - k) * 2;
                #pragma unroll
                for (int ti = 0; ti < 4; ++ti) {
                    const float v = win[8 + ti - off];
                    #pragma unroll
                    for (int ji = 0; ji < 4; ++ji)
                        acc[ji][ti] = fmaf(w[k][ji], v, acc[ji][ti]);
                }
                *(float4*)w[k] = *(const float4*)(wn + k * 1024);
            }
        }
    } else {
        // conv_l: k=9, d=4
        #pragma unroll
        for (int ji = 0; ji < 4; ++ji) {
            const float bv = bl[j0g - 32 + ji];
            #pragma unroll
            for (int ti = 0; ti < 4; ++ti) acc[ji][ti] = bv;
        }
        const float* wp = wl + (j0g - 32);       // + c*32 + k*2048
        float w[9][4];
        #pragma unroll
        for (int k = 0; k < 9; ++k) *(float4*)w[k] = *(const float4*)(wp + k * 2048);
        #pragma unroll 1
        for (int c = 0; c < 64; ++c) {
            const float4* rowq = (const float4*)(&smem[c * 100]);
            float win[36];
            #pragma unroll
            for (int m = 0; m < 9; ++m)
                *(float4*)(&win[4 * m]) = rowq[tt + m];
            const float* wn = wp + (c < 63 ? (c + 1) * 32 : 63 * 32);
            #pragma unroll
            for (int k = 0; k < 9; ++k) {
                #pragma unroll
                for (int ti = 0; ti < 4; ++ti) {
                    const float v = win[4 * k + ti];
                    #pragma unroll
                    for (int ji = 0; ji < 4; ++ji)
                        acc[ji][ti] = fmaf(w[k][ji], v, acc[ji][ti]);
                }
                *(float4*)w[k] = *(const float4*)(wn + k * 2048);
            }
        }
    }

    // relu
    #pragma unroll
    for (int ji = 0; ji < 4; ++ji)
        #pragma unroll
        for (int ti = 0; ti < 4; ++ti) acc[ji][ti] = fmaxf(acc[ji][ti], 0.f);

    // ---- stage h [j][64t] (stride 68), aliasing the input tile ----
    __syncthreads();
    #pragma unroll
    for (int ji = 0; ji < 4; ++ji)
        *(float4*)(&smem[(j0g + ji) * 68 + tt * 4]) =
            make_float4(acc[ji][0], acc[ji][1], acc[ji][2], acc[ji][3]);
    __syncthreads();

    // ---- conv_out 64->64 (no relu): thread = 4 d x 4 t, 4-deep rotation ----
    float o[4][4];
    {
        float bv[4];
        *(float4*)bv = *(const float4*)(bo + j0g);
        #pragma unroll
        for (int di = 0; di < 4; ++di)
            #pragma unroll
            for (int ti = 0; ti < 4; ++ti) o[di][ti] = bv[di];
    }
    float wob[4][4], hb4[4][4];
    #pragma unroll
    for (int p = 0; p < 4; ++p) {
        *(float4*)wob[p] = *(const float4*)(wo + p * 64 + j0g);
        *(float4*)hb4[p] = *(const float4*)(&smem[p * 68 + tt * 4]);
    }
    #pragma unroll 1
    for (int j4 = 0; j4 < 16; ++j4) {
        #pragma unroll
        for (int p = 0; p < 4; ++p) {
            const int j = j4 * 4 + p;
            #pragma unroll
            for (int di = 0; di < 4; ++di)
                #pragma unroll
                for (int ti = 0; ti < 4; ++ti)
                    o[di][ti] = fmaf(wob[p][di], hb4[p][ti], o[di][ti]);
            const int jn = (j + 4 < 64) ? j + 4 : j;
            *(float4*)wob[p] = *(const float4*)(wo + jn * 64 + j0g);
            *(float4*)hb4[p] = *(const float4*)(&smem[jn * 68 + tt * 4]);
        }
    }

    if (!FINAL) {
        float* ob = out + (long)b * 64 * T_LEN + t0 + tt * 4;
        #pragma unroll
        for (int di = 0; di < 4; ++di)
            *(float4*)(ob + (long)(j0g + di) * T_LEN) =
                make_float4(o[di][0], o[di][1], o[di][2], o[di][3]);
    } else {
        // ---- fused head: dense 64->32 + tanh + mean over T ----
        __syncthreads();
        #pragma unroll
        for (int di = 0; di < 4; ++di)
            *(float4*)(&smem[(j0g + di) * 68 + tt * 4]) =
                make_float4(o[di][0], o[di][1], o[di][2], o[di][3]);
        __syncthreads();

        const int tl = tid & 63;
        const int eg = tid >> 6;
        const int e0 = eg * 8;
        float f[8];
        *(float4*)(&f[0]) = *(const float4*)(bd + e0);
        *(float4*)(&f[4]) = *(const float4*)(bd + e0 + 4);

        float wdb[4][8], hb[4];
        #pragma unroll
        for (int p = 0; p < 4; ++p) {
            *(float4*)(&wdb[p][0]) = *(const float4*)(wd + p * 32 + e0);
            *(float4*)(&wdb[p][4]) = *(const float4*)(wd + p * 32 + e0 + 4);
            hb[p] = smem[p * 68 + tl];
        }
        #pragma unroll 1
        for (int d4 = 0; d4 < 16; ++d4) {
            #pragma unroll
            for (int p = 0; p < 4; ++p) {
                const int d = d4 * 4 + p;
                const float v = hb[p];
                #pragma unroll
                for (int e = 0; e < 8; ++e) f[e] = fmaf(wdb[p][e], v, f[e]);
                const int dn = (d + 4 < 64) ? d + 4 : d;
                *(float4*)(&wdb[p][0]) = *(const float4*)(wd + dn * 32 + e0);
                *(float4*)(&wdb[p][4]) = *(const float4*)(wd + dn * 32 + e0 + 4);
                hb[p] = smem[dn * 68 + tl];
            }
        }

        #pragma unroll
        for (int e = 0; e < 8; ++e) {
            float v = tanhf(f[e]) * (1.0f / (float)T_LEN);
            v += __shfl_down(v, 32);
            v += __shfl_down(v, 16);
            v += __shfl_down(v, 8);
            v += __shfl_down(v, 4);
            v += __shfl_down(v, 2);
            v += __shfl_down(v, 1);
            if (tl == 0) atomicAdd(&outp[b * 32 + e0 + e], v);
        }
    }
}

extern "C" void kernel_launch(void* const* d_in, const int* in_sizes, int n_in,
                              void* d_out, int out_size, void* d_ws, size_t ws_size,
                              hipStream_t stream) {
    const float* x     = (const float*)d_in[0];
    const float* gcn_w = (const float*)d_in[1];
    const float* wd    = (const float*)d_in[2];
    const float* bd    = (const float*)d_in[3];
    const float* t1_ws = (const float*)d_in[4];
    const float* t1_bs = (const float*)d_in[5];
    const float* t1_wm = (const float*)d_in[6];
    const float* t1_bm = (const float*)d_in[7];
    const float* t1_wl = (const float*)d_in[8];
    const float* t1_bl = (const float*)d_in[9];
    const float* t1_wo = (const float*)d_in[10];
    const float* t1_bo = (const float*)d_in[11];
    const float* t2_ws = (const float*)d_in[12];
    const float* t2_bs = (const float*)d_in[13];
    const float* t2_wm = (const float*)d_in[14];
    const float* t2_bm = (const float*)d_in[15];
    const float* t2_wl = (const float*)d_in[16];
    const float* t2_bl = (const float*)d_in[17];
    const float* t2_wo = (const float*)d_in[18];
    const float* t2_bo = (const float*)d_in[19];

    float* hp = (float*)d_ws;                          // [16][64][4096]
    float* t1 = hp + (size_t)BATCH * 64 * T_LEN;       // [16][64][4096]

    hipMemsetAsync(d_out, 0, (size_t)out_size * sizeof(float), stream);

    k_gcn_pool<<<dim3(T_LEN / 64, BATCH), 256, 0, stream>>>(x, gcn_w, hp);

    k_mstcn<false><<<dim3(T_LEN / 64, BATCH), 256, 0, stream>>>(
        hp, t1_ws, t1_bs, t1_wm, t1_bm, t1_wl, t1_bl, t1_wo, t1_bo,
        t1, nullptr, nullptr, nullptr);

    k_mstcn<true><<<dim3(T_LEN / 64, BATCH), 256, 0, stream>>>(
        t1, t2_ws, t2_bs, t2_wm, t2_bm, t2_wl, t2_bl, t2_wo, t2_bo,
        nullptr, wd, bd, (float*)d_out);
}

// Round 4
// 390.899 us; speedup vs baseline: 1.0587x; 1.0587x over previous
//
#include <hip/hip_runtime.h>
#include <hip/hip_bf16.h>
#include <math.h>

#define T_LEN 4096
#define BATCH 16

// ---------------------------------------------------------------------------
// k_gcn: adapter + node projections + A_HAT propagation + relu + node-mean.
// thread = (d=lane, 4 timesteps); LDS x-tile [218 c][16 t + pad] so the
// per-c fragment read is ONE wave-uniform ds_read_b128 (broadcast = free)
// feeding 4 FMAs with register weights.  ~65 VGPR -> 7-8 waves/SIMD,
// grid 4096 blocks -> fully oversubscribed.
// Output hp [B][64][T] channel-major.
// ---------------------------------------------------------------------------
__global__ __launch_bounds__(256) void k_gcn(
    const float* __restrict__ x,      // [B][T][218]
    const float* __restrict__ gcn_w,  // [18][64]
    float* __restrict__ hp)           // [B][64][T]
{
    __shared__ float xt[218 * 20];    // [c][16 t], stride 20 (16B-aligned)

    const int b   = blockIdx.y;
    const int t0  = blockIdx.x * 16;
    const int tid = threadIdx.x;

    // stage 16 timesteps (coalesced global read, transposed LDS write)
    const float* xb = x + ((long)b * T_LEN + t0) * 218;
    #pragma unroll 1
    for (int i = tid; i < 16 * 218; i += 256) {
        const int t = i / 218;
        const int c = i - 218 * t;
        xt[c * 20 + t] = xb[i];
    }
    __syncthreads();

    const int d  = tid & 63;
    const int w  = tid >> 6;
    const int tb = w * 4;             // this wave's 4 timesteps

    float wr[18];
    #pragma unroll
    for (int c = 0; c < 18; ++c) wr[c] = gcn_w[c * 64 + d];

    const float cP = 1.0f / 6.0f;
    const float cS = 0.23570226039551584f;   // 1/sqrt(18)
    const float c3 = 1.0f / 3.0f;
    const float cT = 0.4082482904638631f;    // 1/sqrt(6)
    const float cH = 0.5f;

    // palm projection
    float h0[4] = {0.f, 0.f, 0.f, 0.f};
    #pragma unroll
    for (int c = 0; c < 18; ++c) {
        float xv[4];
        *(float4*)xv = *(const float4*)(&xt[c * 20 + tb]);
        #pragma unroll
        for (int ti = 0; ti < 4; ++ti) h0[ti] = fmaf(wr[c], xv[ti], h0[ti]);
    }

    float pool[4] = {0.f, 0.f, 0.f, 0.f};
    float star[4] = {0.f, 0.f, 0.f, 0.f};

    #pragma unroll 1
    for (int f = 0; f < 5; ++f) {
        float hf[4][4];               // [node][ti]
        #pragma unroll
        for (int n = 0; n < 4; ++n) {
            #pragma unroll
            for (int ti = 0; ti < 4; ++ti) hf[n][ti] = 0.f;
            const int cb = 18 + 10 * (4 * f + n);
            #pragma unroll
            for (int c = 0; c < 10; ++c) {
                float xv[4];
                *(float4*)xv = *(const float4*)(&xt[(cb + c) * 20 + tb]);
                #pragma unroll
                for (int ti = 0; ti < 4; ++ti)
                    hf[n][ti] = fmaf(wr[c], xv[ti], hf[n][ti]);
            }
        }
        #pragma unroll
        for (int ti = 0; ti < 4; ++ti) {
            const float ha = hf[0][ti], h2 = hf[1][ti];
            const float h3 = hf[2][ti], he = hf[3][ti];
            star[ti] += ha;
            const float pa = fmaf(cS, h0[ti], c3 * (ha + h2));
            const float pb = c3 * (ha + h2 + h3);
            const float pc = fmaf(cT, he, c3 * (h2 + h3));
            const float pe = fmaf(cT, h3, cH * he);
            pool[ti] += fmaxf(pa, 0.f) + fmaxf(pb, 0.f) +
                        fmaxf(pc, 0.f) + fmaxf(pe, 0.f);
        }
    }

    // finalize + restage [d][t] in LDS for coalesced global write
    __syncthreads();
    #pragma unroll
    for (int ti = 0; ti < 4; ++ti) {
        const float p0 = fmaf(cP, h0[ti], cS * star[ti]);
        xt[d * 20 + tb + ti] = (pool[ti] + fmaxf(p0, 0.f)) * (1.0f / 21.0f);
    }
    __syncthreads();

    float* hpb = hp + (long)b * 64 * T_LEN + t0;
    #pragma unroll 1
    for (int i = tid; i < 64 * 16; i += 256) {
        const int dd = i >> 4;
        const int t  = i & 15;
        hpb[(long)dd * T_LEN + t] = xt[dd * 20 + t];
    }
}

// ---------------------------------------------------------------------------
// k_conv: the three causal dilated convs of one MSTCN, relu, h -> global.
// No trailing barrier: waves retire as they finish (no s/m-wave idling on
// conv_l).  Conv-type -> wave mapping rotated by blockIdx.x so every SIMD
// gets a mix of 3/5/9-tap waves.  Weight registers rotate in place
// (prefetch distance = 1 c-iteration, ~300 cyc of FMA cover).
// ---------------------------------------------------------------------------
__global__ __launch_bounds__(256) void k_conv(
    const float* __restrict__ in,   // [B][64][T]
    const float* __restrict__ ws, const float* __restrict__ bs,
    const float* __restrict__ wm, const float* __restrict__ bm,
    const float* __restrict__ wl, const float* __restrict__ bl,
    float* __restrict__ h)          // [B][64][T] (concat channel-major)
{
    __shared__ float tile[64 * 100]; // [c][32 halo + 64 + pad]

    const int b   = blockIdx.y;
    const int t0  = blockIdx.x * 64;
    const int tid = threadIdx.x;
    const int jl  = ((tid >> 4) + (blockIdx.x << 2)) & 15;  // rotated j-group
    const int tt  = tid & 15;
    const int j0  = jl * 4;

    const float* inb = in + (long)b * 64 * T_LEN;
    #pragma unroll 1
    for (int i = tid; i < 64 * 24; i += 256) {
        const int c = i / 24;
        const int q = i - c * 24;
        const int t = t0 - 32 + q * 4;
        float4 v = make_float4(0.f, 0.f, 0.f, 0.f);
        if (t >= 0) v = *(const float4*)(inb + (long)c * T_LEN + t);
        *(float4*)(&tile[c * 100 + q * 4]) = v;
    }
    __syncthreads();

    float acc[4][4];

    if (jl < 4) {
        // conv_s: k=3, d=1 (concat 0..15)
        #pragma unroll
        for (int ji = 0; ji < 4; ++ji) {
            const float bv = bs[j0 + ji];
            #pragma unroll
            for (int ti = 0; ti < 4; ++ti) acc[ji][ti] = bv;
        }
        const float* wp = ws + j0;
        float w[3][4];
        #pragma unroll
        for (int k = 0; k < 3; ++k) *(float4*)w[k] = *(const float4*)(wp + k * 1024);
        #pragma unroll 1
        for (int c = 0; c < 64; ++c) {
            const float4* rowq = (const float4*)(&tile[c * 100]);
            float win[8];
            *(float4*)(&win[0]) = rowq[tt + 7];
            *(float4*)(&win[4]) = rowq[tt + 8];
            const float* wn = wp + (c < 63 ? (c + 1) * 16 : 63 * 16);
            #pragma unroll
            for (int k = 0; k < 3; ++k) {
                const int off = 2 - k;
                #pragma unroll
                for (int ti = 0; ti < 4; ++ti) {
                    const float v = win[4 + ti - off];
                    #pragma unroll
                    for (int ji = 0; ji < 4; ++ji)
                        acc[ji][ti] = fmaf(w[k][ji], v, acc[ji][ti]);
                }
                *(float4*)w[k] = *(const float4*)(wn + k * 1024);
            }
        }
    } else if (jl < 8) {
        // conv_m: k=5, d=2 (concat 16..31)
        #pragma unroll
        for (int ji = 0; ji < 4; ++ji) {
            const float bv = bm[j0 - 16 + ji];
            #pragma unroll
            for (int ti = 0; ti < 4; ++ti) acc[ji][ti] = bv;
        }
        const float* wp = wm + (j0 - 16);
        float w[5][4];
        #pragma unroll
        for (int k = 0; k < 5; ++k) *(float4*)w[k] = *(const float4*)(wp + k * 1024);
        #pragma unroll 1
        for (int c = 0; c < 64; ++c) {
            const float4* rowq = (const float4*)(&tile[c * 100]);
            float win[12];
            *(float4*)(&win[0]) = rowq[tt + 6];
            *(float4*)(&win[4]) = rowq[tt + 7];
            *(float4*)(&win[8]) = rowq[tt + 8];
            const float* wn = wp + (c < 63 ? (c + 1) * 16 : 63 * 16);
            #pragma unroll
            for (int k = 0; k < 5; ++k) {
                const int off = (4 - k) * 2;
                #pragma unroll
                for (int ti = 0; ti < 4; ++ti) {
                    const float v = win[8 + ti - off];
                    #pragma unroll
                    for (int ji = 0; ji < 4; ++ji)
                        acc[ji][ti] = fmaf(w[k][ji], v, acc[ji][ti]);
                }
                *(float4*)w[k] = *(const float4*)(wn + k * 1024);
            }
        }
    } else {
        // conv_l: k=9, d=4 (concat 32..63)
        #pragma unroll
        for (int ji = 0; ji < 4; ++ji) {
            const float bv = bl[j0 - 32 + ji];
            #pragma unroll
            for (int ti = 0; ti < 4; ++ti) acc[ji][ti] = bv;
        }
        const float* wp = wl + (j0 - 32);
        float w[9][4];
        #pragma unroll
        for (int k = 0; k < 9; ++k) *(float4*)w[k] = *(const float4*)(wp + k * 2048);
        #pragma unroll 1
        for (int c = 0; c < 64; ++c) {
            const float4* rowq = (const float4*)(&tile[c * 100]);
            float win[36];
            #pragma unroll
            for (int m = 0; m < 9; ++m)
                *(float4*)(&win[4 * m]) = rowq[tt + m];
            const float* wn = wp + (c < 63 ? (c + 1) * 32 : 63 * 32);
            #pragma unroll
            for (int k = 0; k < 9; ++k) {
                #pragma unroll
                for (int ti = 0; ti < 4; ++ti) {
                    const float v = win[4 * k + ti];
                    #pragma unroll
                    for (int ji = 0; ji < 4; ++ji)
                        acc[ji][ti] = fmaf(w[k][ji], v, acc[ji][ti]);
                }
                *(float4*)w[k] = *(const float4*)(wn + k * 2048);
            }
        }
    }

    // relu + direct global write, then retire (no barrier)
    float* hb = h + (long)b * 64 * T_LEN + t0 + tt * 4;
    #pragma unroll
    for (int ji = 0; ji < 4; ++ji) {
        float4 v = make_float4(fmaxf(acc[ji][0], 0.f), fmaxf(acc[ji][1], 0.f),
                               fmaxf(acc[ji][2], 0.f), fmaxf(acc[ji][3], 0.f));
        *(float4*)(hb + (long)(j0 + ji) * T_LEN) = v;
    }
}

// ---------------------------------------------------------------------------
// k_convout: 1x1 conv_out 64->64 (no relu).  h-tile AND wo staged in LDS ->
// zero VMEM in the GEMM loop.  FINAL fuses dense 64->32 + tanh + mean.
// ---------------------------------------------------------------------------
template <bool FINAL>
__global__ __launch_bounds__(256) void k_convout(
    const float* __restrict__ h,    // [B][64][T]
    const float* __restrict__ wo,   // [1][64][64]
    const float* __restrict__ bo,   // [64]
    float* __restrict__ out,        // [B][64][T]  (FINAL=false)
    const float* __restrict__ wd,   // [64][32]    (FINAL=true)
    const float* __restrict__ bd,   // [32]
    float* __restrict__ outp)       // [B][32]     (FINAL=true)
{
    __shared__ float hs[64 * 68];
    __shared__ float wos[64 * 64];

    const int b   = blockIdx.y;
    const int t0  = blockIdx.x * 64;
    const int tid = threadIdx.x;
    const int dg  = tid >> 4;
    const int tt  = tid & 15;
    const int d0  = dg * 4;

    const float* hbase = h + (long)b * 64 * T_LEN + t0;
    #pragma unroll 1
    for (int i = tid; i < 1024; i += 256) {
        const int row = i >> 4;
        const int col = (i & 15) * 4;
        *(float4*)(&hs[row * 68 + col]) = *(const float4*)(hbase + (long)row * T_LEN + col);
    }
    #pragma unroll 1
    for (int i = tid; i < 1024; i += 256)
        *(float4*)(&wos[i * 4]) = *(const float4*)(wo + i * 4);
    __syncthreads();

    float o[4][4];
    {
        float bv[4];
        *(float4*)bv = *(const float4*)(bo + d0);
        #pragma unroll
        for (int di = 0; di < 4; ++di)
            #pragma unroll
            for (int ti = 0; ti < 4; ++ti) o[di][ti] = bv[di];
    }
    #pragma unroll 1
    for (int j4 = 0; j4 < 16; ++j4) {
        #pragma unroll
        for (int p = 0; p < 4; ++p) {
            const int j = j4 * 4 + p;
            float wv[4], hv[4];
            *(float4*)wv = *(const float4*)(&wos[j * 64 + d0]);
            *(float4*)hv = *(const float4*)(&hs[j * 68 + tt * 4]);
            #pragma unroll
            for (int di = 0; di < 4; ++di)
                #pragma unroll
                for (int ti = 0; ti < 4; ++ti)
                    o[di][ti] = fmaf(wv[di], hv[ti], o[di][ti]);
        }
    }

    if (!FINAL) {
        float* ob = out + (long)b * 64 * T_LEN + t0 + tt * 4;
        #pragma unroll
        for (int di = 0; di < 4; ++di)
            *(float4*)(ob + (long)(d0 + di) * T_LEN) =
                make_float4(o[di][0], o[di][1], o[di][2], o[di][3]);
    } else {
        // fused head: dense 64->32 + tanh + mean over T
        __syncthreads();
        #pragma unroll
        for (int di = 0; di < 4; ++di)
            *(float4*)(&hs[(d0 + di) * 68 + tt * 4]) =
                make_float4(o[di][0], o[di][1], o[di][2], o[di][3]);
        __syncthreads();

        const int tl = tid & 63;
        const int eg = tid >> 6;
        const int e0 = eg * 8;
        float f[8];
        *(float4*)(&f[0]) = *(const float4*)(bd + e0);
        *(float4*)(&f[4]) = *(const float4*)(bd + e0 + 4);

        float wdb[4][8], hb[4];
        #pragma unroll
        for (int p = 0; p < 4; ++p) {
            *(float4*)(&wdb[p][0]) = *(const float4*)(wd + p * 32 + e0);
            *(float4*)(&wdb[p][4]) = *(const float4*)(wd + p * 32 + e0 + 4);
            hb[p] = hs[p * 68 + tl];
        }
        #pragma unroll 1
        for (int d4 = 0; d4 < 16; ++d4) {
            #pragma unroll
            for (int p = 0; p < 4; ++p) {
                const int d = d4 * 4 + p;
                const float v = hb[p];
                #pragma unroll
                for (int e = 0; e < 8; ++e) f[e] = fmaf(wdb[p][e], v, f[e]);
                const int dn = (d + 4 < 64) ? d + 4 : d;
                *(float4*)(&wdb[p][0]) = *(const float4*)(wd + dn * 32 + e0);
                *(float4*)(&wdb[p][4]) = *(const float4*)(wd + dn * 32 + e0 + 4);
                hb[p] = hs[dn * 68 + tl];
            }
        }

        #pragma unroll
        for (int e = 0; e < 8; ++e) {
            float v = tanhf(f[e]) * (1.0f / (float)T_LEN);
            v += __shfl_down(v, 32);
            v += __shfl_down(v, 16);
            v += __shfl_down(v, 8);
            v += __shfl_down(v, 4);
            v += __shfl_down(v, 2);
            v += __shfl_down(v, 1);
            if (tl == 0) atomicAdd(&outp[b * 32 + e0 + e], v);
        }
    }
}

extern "C" void kernel_launch(void* const* d_in, const int* in_sizes, int n_in,
                              void* d_out, int out_size, void* d_ws, size_t ws_size,
                              hipStream_t stream) {
    const float* x     = (const float*)d_in[0];
    const float* gcn_w = (const float*)d_in[1];
    const float* wd    = (const float*)d_in[2];
    const float* bd    = (const float*)d_in[3];
    const float* t1_ws = (const float*)d_in[4];
    const float* t1_bs = (const float*)d_in[5];
    const float* t1_wm = (const float*)d_in[6];
    const float* t1_bm = (const float*)d_in[7];
    const float* t1_wl = (const float*)d_in[8];
    const float* t1_bl = (const float*)d_in[9];
    const float* t1_wo = (const float*)d_in[10];
    const float* t1_bo = (const float*)d_in[11];
    const float* t2_ws = (const float*)d_in[12];
    const float* t2_bs = (const float*)d_in[13];
    const float* t2_wm = (const float*)d_in[14];
    const float* t2_bm = (const float*)d_in[15];
    const float* t2_wl = (const float*)d_in[16];
    const float* t2_bl = (const float*)d_in[17];
    const float* t2_wo = (const float*)d_in[18];
    const float* t2_bo = (const float*)d_in[19];

    float* b0 = (float*)d_ws;                          // [16][64][4096]
    float* b1 = b0 + (size_t)BATCH * 64 * T_LEN;       // [16][64][4096]

    hipMemsetAsync(d_out, 0, (size_t)out_size * sizeof(float), stream);

    k_gcn<<<dim3(T_LEN / 16, BATCH), 256, 0, stream>>>(x, gcn_w, b0);

    k_conv<<<dim3(T_LEN / 64, BATCH), 256, 0, stream>>>(
        b0, t1_ws, t1_bs, t1_wm, t1_bm, t1_wl, t1_bl, b1);
    k_convout<false><<<dim3(T_LEN / 64, BATCH), 256, 0, stream>>>(
        b1, t1_wo, t1_bo, b0, nullptr, nullptr, nullptr);

    k_conv<<<dim3(T_LEN / 64, BATCH), 256, 0, stream>>>(
        b0, t2_ws, t2_bs, t2_wm, t2_bm, t2_wl, t2_bl, b1);
    k_convout<true><<<dim3(T_LEN / 64, BATCH), 256, 0, stream>>>(
        b1, t2_wo, t2_bo, nullptr, wd, bd, (float*)d_out);
}